// Round 3
// baseline (234.928 us; speedup 1.0000x reference)
//
#include <hip/hip_runtime.h>

#define NWIN 4096
#define DIM 96
#define HEADS 6
#define NTOK 64

typedef __bf16 bf16x8 __attribute__((ext_vector_type(8)));
typedef __bf16 bf16x4 __attribute__((ext_vector_type(4)));
typedef float  f32x4  __attribute__((ext_vector_type(4)));

// d_ws layout
#define WS_QKVW 0                   // 288*96 bf16 = 55296 B
#define WS_PROJW 55296              // 96*96 bf16  = 18432 B
#define WS_BIAS 73728               // 6*16*64 float4 = 98304 B (frag-ordered)
#define WS_TOTAL 172032

__device__ __forceinline__ f32x4 mfma16(bf16x8 a, bf16x8 b, f32x4 c) {
  return __builtin_amdgcn_mfma_f32_16x16x32_bf16(a, b, c, 0, 0, 0);
}

__device__ __forceinline__ bf16x8 cvt8(const float* p) {
  const float4* q = (const float4*)p;
  float4 a = q[0];
  float4 b = q[1];
  bf16x8 r;
  r[0] = (__bf16)a.x; r[1] = (__bf16)a.y; r[2] = (__bf16)a.z; r[3] = (__bf16)a.w;
  r[4] = (__bf16)b.x; r[5] = (__bf16)b.y; r[6] = (__bf16)b.z; r[7] = (__bf16)b.w;
  return r;
}

// Pre-pass: weights -> bf16; bias gathered into MFMA-fragment order:
// bias[((h*16 + bq*4 + a)*64 + lane)*4 + r] = rpb[rpi[qrow*64+kcol]*6+h]
// with qrow = 16*bq + (lane&15), kcol = 16*a + 4*(lane>>4) + r.
__global__ void prep_kernel(const float* __restrict__ qkv_w,
                            const float* __restrict__ proj_w,
                            const float* __restrict__ rpb,
                            const int* __restrict__ rpi,
                            char* __restrict__ ws) {
  int i = blockIdx.x * blockDim.x + threadIdx.x;
  __bf16* qw = (__bf16*)(ws + WS_QKVW);
  __bf16* pw = (__bf16*)(ws + WS_PROJW);
  float* bias = (float*)(ws + WS_BIAS);
  if (i < 288 * 96) qw[i] = (__bf16)qkv_w[i];
  int j = i - 288 * 96;
  if (j >= 0 && j < 96 * 96) pw[j] = (__bf16)proj_w[j];
  int t = i - (288 * 96 + 96 * 96);
  if (t >= 0 && t < HEADS * 16 * 64 * 4) {
    int r = t & 3;
    int lane = (t >> 2) & 63;
    int ba = (t >> 8) & 15;
    int h = t >> 12;
    int bq = ba >> 2, a = ba & 3;
    int l16 = lane & 15, lq = lane >> 4;
    int qrow = 16 * bq + l16;
    int kcol = 16 * a + 4 * lq + r;
    bias[t] = rpb[rpi[qrow * 64 + kcol] * HEADS + h];
  }
}

// One block = one window; 6 waves, wave w owns head w until proj.
// LDS per head: buf[64][24] (k, then q, then P-tile overlay) + vT[16][72]
// = 5376 B; block total 32256 B -> 5 blocks/CU LDS cap.
template <bool USE_WS>
__global__ __launch_bounds__(384, 7) void win_attn(
    const float* __restrict__ x,
    const int* __restrict__ rpi,
    const float* __restrict__ qkv_w,
    const float* __restrict__ qkv_b,
    const float* __restrict__ proj_w,
    const float* __restrict__ proj_b,
    const float* __restrict__ rpb,
    const char* __restrict__ ws,
    float* __restrict__ out) {
  __shared__ __align__(16) __bf16 lds[HEADS * 2688];

  const int tid = (int)threadIdx.x;
  const int wv = tid >> 6;
  const int lane = tid & 63;
  const int l16 = lane & 15;
  const int lq = lane >> 4;
  const int b = (int)blockIdx.x;

  __bf16* buf = lds + wv * 2688;   // [64][24]: k -> q -> Pt overlay
  __bf16* vh = buf + 1536;         // vT[16][72]
  __bf16* Pt = buf;                // [16][72] overlay (buf dead by then)
  __bf16* ao = lds;                // [64][104] overlay (post-barrier)

  const float* xw = x + (size_t)b * (NTOK * DIM);
  const __bf16* qwb = (const __bf16*)(ws + WS_QKVW);
  const __bf16* pwb = (const __bf16*)(ws + WS_PROJW);
  const float4* bias4 = (const float4*)(ws + WS_BIAS) + (wv << 10);

  bf16x8 zf = {};

  // ---- x fragments (serve as A- or B-frags; identical layout) ----
  bf16x8 xa[4][3];
#pragma unroll
  for (int mt = 0; mt < 4; ++mt)
#pragma unroll
    for (int ks = 0; ks < 3; ++ks)
      xa[mt][ks] = cvt8(xw + (16 * mt + l16) * DIM + 32 * ks + 8 * lq);

  // ---- K phase: D = Wk * X^T -> D[feature][token], b64 stores ----
  {
    const int frow = (HEADS + wv) * 16;
    bf16x8 wb[3];
#pragma unroll
    for (int ks = 0; ks < 3; ++ks) {
      if constexpr (USE_WS)
        wb[ks] = *(const bf16x8*)(qwb + (frow + l16) * 96 + 32 * ks + 8 * lq);
      else
        wb[ks] = cvt8(qkv_w + (frow + l16) * 96 + 32 * ks + 8 * lq);
    }
    const float4 kb4 = *(const float4*)(qkv_b + frow + 4 * lq);
    const float kbv[4] = {kb4.x, kb4.y, kb4.z, kb4.w};
#pragma unroll
    for (int mt = 0; mt < 4; ++mt) {
      f32x4 acc = {0.f, 0.f, 0.f, 0.f};
#pragma unroll
      for (int ks = 0; ks < 3; ++ks) acc = mfma16(wb[ks], xa[mt][ks], acc);
      bf16x4 t;  // col=l16 token, row=4lq+r feature -> k[token][feature]
#pragma unroll
      for (int r = 0; r < 4; ++r) t[r] = (__bf16)(acc[r] + kbv[r]);
      *(bf16x4*)(buf + (16 * mt + l16) * 24 + 4 * lq) = t;
    }
  }
  asm volatile("s_waitcnt lgkmcnt(0)" ::: "memory");

  bf16x8 kb[4];
#pragma unroll
  for (int a = 0; a < 4; ++a)
    kb[a] = (lq < 2) ? *(const bf16x8*)(buf + (16 * a + l16) * 24 + 8 * lq) : zf;

  // ---- V phase (overlaps kb-read drain): D = X * Wv^T ----
  {
    const int frow = (2 * HEADS + wv) * 16;
    bf16x8 wb[3];
#pragma unroll
    for (int ks = 0; ks < 3; ++ks) {
      if constexpr (USE_WS)
        wb[ks] = *(const bf16x8*)(qwb + (frow + l16) * 96 + 32 * ks + 8 * lq);
      else
        wb[ks] = cvt8(qkv_w + (frow + l16) * 96 + 32 * ks + 8 * lq);
    }
    const float vb = qkv_b[frow + l16];
#pragma unroll
    for (int mt = 0; mt < 4; ++mt) {
      f32x4 acc = {0.f, 0.f, 0.f, 0.f};
#pragma unroll
      for (int ks = 0; ks < 3; ++ks) acc = mfma16(xa[mt][ks], wb[ks], acc);
      bf16x4 t;  // row=token, col=l16 feature -> vT[feature][token]
#pragma unroll
      for (int r = 0; r < 4; ++r) t[r] = (__bf16)(acc[r] + vb);
      *(bf16x4*)(vh + l16 * 72 + 16 * mt + 4 * lq) = t;
    }
  }
  asm volatile("s_waitcnt lgkmcnt(0)" ::: "memory");  // kb reads + vT done

  // ---- Q phase: D = Wq * X^T, scaled; overwrites buf ----
  {
    const int frow = wv * 16;
    bf16x8 wb[3];
#pragma unroll
    for (int ks = 0; ks < 3; ++ks) {
      if constexpr (USE_WS)
        wb[ks] = *(const bf16x8*)(qwb + (frow + l16) * 96 + 32 * ks + 8 * lq);
      else
        wb[ks] = cvt8(qkv_w + (frow + l16) * 96 + 32 * ks + 8 * lq);
    }
    const float4 qb4 = *(const float4*)(qkv_b + frow + 4 * lq);
    const float qbv[4] = {qb4.x, qb4.y, qb4.z, qb4.w};
#pragma unroll
    for (int mt = 0; mt < 4; ++mt) {
      f32x4 acc = {0.f, 0.f, 0.f, 0.f};
#pragma unroll
      for (int ks = 0; ks < 3; ++ks) acc = mfma16(wb[ks], xa[mt][ks], acc);
      bf16x4 t;
#pragma unroll
      for (int r = 0; r < 4; ++r) t[r] = (__bf16)((acc[r] + qbv[r]) * 0.25f);
      *(bf16x4*)(buf + (16 * mt + l16) * 24 + 4 * lq) = t;
    }
  }
  asm volatile("s_waitcnt lgkmcnt(0)" ::: "memory");

  bf16x8 qbf[4];
#pragma unroll
  for (int bq = 0; bq < 4; ++bq)
    qbf[bq] = (lq < 2) ? *(const bf16x8*)(buf + (16 * bq + l16) * 24 + 8 * lq) : zf;
  bf16x8 vbf[2];
#pragma unroll
  for (int c = 0; c < 2; ++c)
    vbf[c] = *(const bf16x8*)(vh + l16 * 72 + 32 * c + 8 * lq);
  asm volatile("s_waitcnt lgkmcnt(0)" ::: "memory");  // buf free for Pt

  f32x4 oacc[4];
#pragma unroll
  for (int bq = 0; bq < 4; ++bq) {
    f32x4 z4 = {0.f, 0.f, 0.f, 0.f};
    oacc[bq] = z4;
  }

  // ---- attention per q-tile: S^T = K*Q^T with bias C-init; no-max softmax ----
#pragma unroll
  for (int bq = 0; bq < 4; ++bq) {
    f32x4 bc[4];
    if constexpr (USE_WS) {
#pragma unroll
      for (int a = 0; a < 4; ++a) {
        float4 t = bias4[(bq * 4 + a) * 64 + lane];
        bc[a][0] = t.x; bc[a][1] = t.y; bc[a][2] = t.z; bc[a][3] = t.w;
      }
    } else {
#pragma unroll
      for (int a = 0; a < 4; ++a)
#pragma unroll
        for (int r = 0; r < 4; ++r)
          bc[a][r] = rpb[rpi[(16 * bq + l16) * 64 + 16 * a + 4 * lq + r] * HEADS + wv];
    }

    f32x4 s[4];
#pragma unroll
    for (int a = 0; a < 4; ++a) s[a] = mfma16(kb[a], qbf[bq], bc[a]);

    // logits are tiny (|s| << 1): exp directly, no max subtraction
    float tp[4];
#pragma unroll
    for (int a = 0; a < 4; ++a) {
      float t0 = 0.f;
#pragma unroll
      for (int r = 0; r < 4; ++r) {
        float e = __expf(s[a][r]);
        s[a][r] = e;
        t0 += e;
      }
      tp[a] = t0;
    }
    float tsum = (tp[0] + tp[1]) + (tp[2] + tp[3]);
    tsum += __shfl_xor(tsum, 16);
    tsum += __shfl_xor(tsum, 32);
    const float rv = 1.0f / tsum;

#pragma unroll
    for (int a = 0; a < 4; ++a) {
      bf16x4 p;
#pragma unroll
      for (int r = 0; r < 4; ++r) p[r] = (__bf16)(s[a][r] * rv);
      *(bf16x4*)(Pt + l16 * 72 + 16 * a + 4 * lq) = p;
    }
    asm volatile("s_waitcnt lgkmcnt(0)" ::: "memory");

#pragma unroll
    for (int c = 0; c < 2; ++c) {
      const bf16x8 pa = *(const bf16x8*)(Pt + l16 * 72 + 32 * c + 8 * lq);
      oacc[bq] = mfma16(pa, vbf[c], oacc[bq]);
    }
    asm volatile("s_waitcnt lgkmcnt(0)" ::: "memory");  // drain before overwrite
  }

  // ---- stage attn-out (ao overlays everything; barrier both sides) ----
  __syncthreads();
#pragma unroll
  for (int mt = 0; mt < 4; ++mt)
#pragma unroll
    for (int r = 0; r < 4; ++r)
      ao[(16 * mt + 4 * lq + r) * 104 + 16 * wv + l16] = (__bf16)oacc[mt][r];
  __syncthreads();

  // ---- proj ----
  bf16x8 wpb[3];
#pragma unroll
  for (int ks = 0; ks < 3; ++ks) {
    if constexpr (USE_WS)
      wpb[ks] = *(const bf16x8*)(pwb + (16 * wv + l16) * 96 + 32 * ks + 8 * lq);
    else
      wpb[ks] = cvt8(proj_w + (16 * wv + l16) * 96 + 32 * ks + 8 * lq);
  }
  const float pb2 = proj_b[16 * wv + l16];
  float* outw = out + (size_t)b * (NTOK * DIM);
#pragma unroll
  for (int mt = 0; mt < 4; ++mt) {
    f32x4 acc = {0.f, 0.f, 0.f, 0.f};
#pragma unroll
    for (int ks = 0; ks < 3; ++ks) {
      bf16x8 aa = *(const bf16x8*)(ao + (16 * mt + l16) * 104 + 32 * ks + 8 * lq);
      acc = mfma16(aa, wpb[ks], acc);
    }
#pragma unroll
    for (int r = 0; r < 4; ++r)
      outw[(16 * mt + 4 * lq + r) * 96 + 16 * wv + l16] = acc[r] + pb2;
  }
}

extern "C" void kernel_launch(void* const* d_in, const int* in_sizes, int n_in,
                              void* d_out, int out_size, void* d_ws, size_t ws_size,
                              hipStream_t stream) {
  const float* x      = (const float*)d_in[0];
  const int*   rpi    = (const int*)d_in[1];
  const float* qkv_w  = (const float*)d_in[2];
  const float* qkv_b  = (const float*)d_in[3];
  const float* proj_w = (const float*)d_in[4];
  const float* proj_b = (const float*)d_in[5];
  const float* rpb    = (const float*)d_in[6];
  float* out = (float*)d_out;

  if (ws_size >= (size_t)WS_TOTAL) {
    prep_kernel<<<240, 256, 0, stream>>>(qkv_w, proj_w, rpb, rpi, (char*)d_ws);
    win_attn<true><<<NWIN, 384, 0, stream>>>(x, rpi, qkv_w, qkv_b, proj_w,
                                             proj_b, rpb, (const char*)d_ws, out);
  } else {
    win_attn<false><<<NWIN, 384, 0, stream>>>(x, rpi, qkv_w, qkv_b, proj_w,
                                              proj_b, rpb, (const char*)d_ws, out);
  }
}

// Round 4
// 86.621 us; speedup vs baseline: 2.7121x; 2.7121x over previous
//
#include <hip/hip_runtime.h>

#define NWIN 4096
#define DIM 96
#define HEADS 6
#define NTOK 64

typedef __bf16 bf16x8 __attribute__((ext_vector_type(8)));
typedef __bf16 bf16x4 __attribute__((ext_vector_type(4)));
typedef float  f32x4  __attribute__((ext_vector_type(4)));

// d_ws layout
#define WS_QKVW 0                   // 288*96 bf16 = 55296 B
#define WS_PROJW 55296              // 96*96 bf16  = 18432 B
#define WS_BIAS 73728               // 6*16*64 float4 = 98304 B (frag-ordered)
#define WS_TOTAL 172032

__device__ __forceinline__ f32x4 mfma16(bf16x8 a, bf16x8 b, f32x4 c) {
  return __builtin_amdgcn_mfma_f32_16x16x32_bf16(a, b, c, 0, 0, 0);
}

__device__ __forceinline__ bf16x8 cvt8(const float* p) {
  const float4* q = (const float4*)p;
  float4 a = q[0];
  float4 b = q[1];
  bf16x8 r;
  r[0] = (__bf16)a.x; r[1] = (__bf16)a.y; r[2] = (__bf16)a.z; r[3] = (__bf16)a.w;
  r[4] = (__bf16)b.x; r[5] = (__bf16)b.y; r[6] = (__bf16)b.z; r[7] = (__bf16)b.w;
  return r;
}

// Pre-pass: weights -> bf16; bias gathered into MFMA-fragment order:
// bias[((h*16 + bq*4 + a)*64 + lane)*4 + r] = rpb[rpi[qrow*64+kcol]*6+h]
// with qrow = 16*bq + (lane&15), kcol = 16*a + 4*(lane>>4) + r.
__global__ void prep_kernel(const float* __restrict__ qkv_w,
                            const float* __restrict__ proj_w,
                            const float* __restrict__ rpb,
                            const int* __restrict__ rpi,
                            char* __restrict__ ws) {
  int i = blockIdx.x * blockDim.x + threadIdx.x;
  __bf16* qw = (__bf16*)(ws + WS_QKVW);
  __bf16* pw = (__bf16*)(ws + WS_PROJW);
  float* bias = (float*)(ws + WS_BIAS);
  if (i < 288 * 96) qw[i] = (__bf16)qkv_w[i];
  int j = i - 288 * 96;
  if (j >= 0 && j < 96 * 96) pw[j] = (__bf16)proj_w[j];
  int t = i - (288 * 96 + 96 * 96);
  if (t >= 0 && t < HEADS * 16 * 64 * 4) {
    int r = t & 3;
    int lane = (t >> 2) & 63;
    int ba = (t >> 8) & 15;
    int h = t >> 12;
    int bq = ba >> 2, a = ba & 3;
    int l16 = lane & 15, lq = lane >> 4;
    int qrow = 16 * bq + l16;
    int kcol = 16 * a + 4 * lq + r;
    bias[t] = rpb[rpi[qrow * 64 + kcol] * HEADS + h];
  }
}

// One block = one window; 6 waves, wave w owns head w until proj.
// LDS: xfrag 12288 B (shared x fragments; ao[64][104]=13312 B overlays it
// after the post-Q barrier) + per-head buf[64][24] (k->q) 3072 B +
// vT[16][72] (v -> Pt overlay) 2304 B. Total 13312 + 6*5376 = 45568 B.
template <bool USE_WS>
__global__ __launch_bounds__(384, 8) void win_attn(
    const float* __restrict__ x,
    const int* __restrict__ rpi,
    const float* __restrict__ qkv_w,
    const float* __restrict__ qkv_b,
    const float* __restrict__ proj_w,
    const float* __restrict__ proj_b,
    const float* __restrict__ rpb,
    const char* __restrict__ ws,
    float* __restrict__ out) {
  __shared__ __align__(16) __bf16 lds[22784];

  const int tid = (int)threadIdx.x;
  const int wv = tid >> 6;
  const int lane = tid & 63;
  const int l16 = lane & 15;
  const int lq = lane >> 4;
  const int b = (int)blockIdx.x;

  __bf16* xfrag = lds;                   // 12 frags * 512 bf16
  __bf16* ao = lds;                      // [64][104] overlay (post-barrier)
  __bf16* buf = lds + 6656 + wv * 2688;  // [64][24]: k -> q
  __bf16* vh = buf + 1536;               // vT[16][72] -> Pt[16][72] overlay
  __bf16* Pt = vh;

  const float* xw = x + (size_t)b * (NTOK * DIM);
  const __bf16* qwb = (const __bf16*)(ws + WS_QKVW);
  const __bf16* pwb = (const __bf16*)(ws + WS_PROJW);
  const float4* bias4 = (const float4*)(ws + WS_BIAS) + (wv << 10);

  bf16x8 zf = {};

  // ---- stage x fragments once per block (wave wv does frags 2wv, 2wv+1) ----
#pragma unroll
  for (int ff = 0; ff < 2; ++ff) {
    const int f = 2 * wv + ff;
    const int mt = f / 3, ks = f - 3 * mt;
    bf16x8 v = cvt8(xw + (16 * mt + l16) * DIM + 32 * ks + 8 * lq);
    *(bf16x8*)(xfrag + (f * 64 + lane) * 8) = v;
  }
  __syncthreads();

#define XV(mt, ks) (*(const bf16x8*)(xfrag + (((mt) * 3 + (ks)) * 64 + lane) * 8))

  // ---- K phase: D = Wk * X^T -> k[token][feature], b64 stores ----
  {
    const int frow = (HEADS + wv) * 16;
    bf16x8 wb[3];
#pragma unroll
    for (int ks = 0; ks < 3; ++ks) {
      if constexpr (USE_WS)
        wb[ks] = *(const bf16x8*)(qwb + (frow + l16) * 96 + 32 * ks + 8 * lq);
      else
        wb[ks] = cvt8(qkv_w + (frow + l16) * 96 + 32 * ks + 8 * lq);
    }
    const float4 kb4 = *(const float4*)(qkv_b + frow + 4 * lq);
    const float kbv[4] = {kb4.x, kb4.y, kb4.z, kb4.w};
#pragma unroll
    for (int mt = 0; mt < 4; ++mt) {
      f32x4 acc = {0.f, 0.f, 0.f, 0.f};
#pragma unroll
      for (int ks = 0; ks < 3; ++ks) acc = mfma16(wb[ks], XV(mt, ks), acc);
      bf16x4 t;
#pragma unroll
      for (int r = 0; r < 4; ++r) t[r] = (__bf16)(acc[r] + kbv[r]);
      *(bf16x4*)(buf + (16 * mt + l16) * 24 + 4 * lq) = t;
    }
  }
  asm volatile("s_waitcnt lgkmcnt(0)" ::: "memory");

  bf16x8 kb[4];
#pragma unroll
  for (int a = 0; a < 4; ++a)
    kb[a] = (lq < 2) ? *(const bf16x8*)(buf + (16 * a + l16) * 24 + 8 * lq) : zf;

  // ---- V phase: D = X * Wv^T -> vT[feature][token] ----
  {
    const int frow = (2 * HEADS + wv) * 16;
    bf16x8 wb[3];
#pragma unroll
    for (int ks = 0; ks < 3; ++ks) {
      if constexpr (USE_WS)
        wb[ks] = *(const bf16x8*)(qwb + (frow + l16) * 96 + 32 * ks + 8 * lq);
      else
        wb[ks] = cvt8(qkv_w + (frow + l16) * 96 + 32 * ks + 8 * lq);
    }
    const float vb = qkv_b[frow + l16];
#pragma unroll
    for (int mt = 0; mt < 4; ++mt) {
      f32x4 acc = {0.f, 0.f, 0.f, 0.f};
#pragma unroll
      for (int ks = 0; ks < 3; ++ks) acc = mfma16(XV(mt, ks), wb[ks], acc);
      bf16x4 t;
#pragma unroll
      for (int r = 0; r < 4; ++r) t[r] = (__bf16)(acc[r] + vb);
      *(bf16x4*)(vh + l16 * 72 + 16 * mt + 4 * lq) = t;
    }
  }
  asm volatile("s_waitcnt lgkmcnt(0)" ::: "memory");

  bf16x8 vbf[2];
#pragma unroll
  for (int c = 0; c < 2; ++c)
    vbf[c] = *(const bf16x8*)(vh + l16 * 72 + 32 * c + 8 * lq);

  // ---- Q phase: D = Wq * X^T, scaled; overwrites buf (k already in regs) ----
  {
    const int frow = wv * 16;
    bf16x8 wb[3];
#pragma unroll
    for (int ks = 0; ks < 3; ++ks) {
      if constexpr (USE_WS)
        wb[ks] = *(const bf16x8*)(qwb + (frow + l16) * 96 + 32 * ks + 8 * lq);
      else
        wb[ks] = cvt8(qkv_w + (frow + l16) * 96 + 32 * ks + 8 * lq);
    }
    const float4 qb4 = *(const float4*)(qkv_b + frow + 4 * lq);
    const float qbv[4] = {qb4.x, qb4.y, qb4.z, qb4.w};
#pragma unroll
    for (int mt = 0; mt < 4; ++mt) {
      f32x4 acc = {0.f, 0.f, 0.f, 0.f};
#pragma unroll
      for (int ks = 0; ks < 3; ++ks) acc = mfma16(wb[ks], XV(mt, ks), acc);
      bf16x4 t;
#pragma unroll
      for (int r = 0; r < 4; ++r) t[r] = (__bf16)((acc[r] + qbv[r]) * 0.25f);
      *(bf16x4*)(buf + (16 * mt + l16) * 24 + 4 * lq) = t;
    }
  }
#undef XV
  // all waves done reading xfrag before ao overlays it
  __syncthreads();

  // ---- attention per q-tile: S^T = K*Q^T, bias C-init; no-max softmax ----
#pragma unroll
  for (int bq = 0; bq < 4; ++bq) {
    f32x4 s[4];
    if constexpr (USE_WS) {
#pragma unroll
      for (int a = 0; a < 4; ++a) {
        float4 t = bias4[(bq * 4 + a) * 64 + lane];
        s[a][0] = t.x; s[a][1] = t.y; s[a][2] = t.z; s[a][3] = t.w;
      }
    } else {
#pragma unroll
      for (int a = 0; a < 4; ++a)
#pragma unroll
        for (int r = 0; r < 4; ++r)
          s[a][r] = rpb[rpi[(16 * bq + l16) * 64 + 16 * a + 4 * lq + r] * HEADS + wv];
    }

    const bf16x8 qv =
        (lq < 2) ? *(const bf16x8*)(buf + (16 * bq + l16) * 24 + 8 * lq) : zf;
#pragma unroll
    for (int a = 0; a < 4; ++a) s[a] = mfma16(kb[a], qv, s[a]);

    // logits tiny (|s| << 1): exp directly, no max subtraction
    float tp[4];
#pragma unroll
    for (int a = 0; a < 4; ++a) {
      float t0 = 0.f;
#pragma unroll
      for (int r = 0; r < 4; ++r) {
        float e = __expf(s[a][r]);
        s[a][r] = e;
        t0 += e;
      }
      tp[a] = t0;
    }
    float tsum = (tp[0] + tp[1]) + (tp[2] + tp[3]);
    tsum += __shfl_xor(tsum, 16);
    tsum += __shfl_xor(tsum, 32);
    const float rv = 1.0f / tsum;

#pragma unroll
    for (int a = 0; a < 4; ++a) {
      bf16x4 p;
#pragma unroll
      for (int r = 0; r < 4; ++r) p[r] = (__bf16)(s[a][r] * rv);
      *(bf16x4*)(Pt + l16 * 72 + 16 * a + 4 * lq) = p;
    }
    asm volatile("s_waitcnt lgkmcnt(0)" ::: "memory");

    f32x4 oacc = {0.f, 0.f, 0.f, 0.f};
#pragma unroll
    for (int c = 0; c < 2; ++c) {
      const bf16x8 pa = *(const bf16x8*)(Pt + l16 * 72 + 32 * c + 8 * lq);
      oacc = mfma16(pa, vbf[c], oacc);
    }
    asm volatile("s_waitcnt lgkmcnt(0)" ::: "memory");  // drain before overwrite

    // stage this tile's attn-out immediately (ao region free post-barrier)
#pragma unroll
    for (int r = 0; r < 4; ++r)
      ao[(16 * bq + 4 * lq + r) * 104 + 16 * wv + l16] = (__bf16)oacc[r];
  }
  __syncthreads();

  // ---- proj ----
  bf16x8 wpb[3];
#pragma unroll
  for (int ks = 0; ks < 3; ++ks) {
    if constexpr (USE_WS)
      wpb[ks] = *(const bf16x8*)(pwb + (16 * wv + l16) * 96 + 32 * ks + 8 * lq);
    else
      wpb[ks] = cvt8(proj_w + (16 * wv + l16) * 96 + 32 * ks + 8 * lq);
  }
  const float pb2 = proj_b[16 * wv + l16];
  float* outw = out + (size_t)b * (NTOK * DIM);
#pragma unroll
  for (int mt = 0; mt < 4; ++mt) {
    f32x4 acc = {0.f, 0.f, 0.f, 0.f};
#pragma unroll
    for (int ks = 0; ks < 3; ++ks) {
      bf16x8 aa = *(const bf16x8*)(ao + (16 * mt + l16) * 104 + 32 * ks + 8 * lq);
      acc = mfma16(aa, wpb[ks], acc);
    }
#pragma unroll
    for (int r = 0; r < 4; ++r)
      outw[(16 * mt + 4 * lq + r) * 96 + 16 * wv + l16] = acc[r] + pb2;
  }
}

extern "C" void kernel_launch(void* const* d_in, const int* in_sizes, int n_in,
                              void* d_out, int out_size, void* d_ws, size_t ws_size,
                              hipStream_t stream) {
  const float* x      = (const float*)d_in[0];
  const int*   rpi    = (const int*)d_in[1];
  const float* qkv_w  = (const float*)d_in[2];
  const float* qkv_b  = (const float*)d_in[3];
  const float* proj_w = (const float*)d_in[4];
  const float* proj_b = (const float*)d_in[5];
  const float* rpb    = (const float*)d_in[6];
  float* out = (float*)d_out;

  if (ws_size >= (size_t)WS_TOTAL) {
    prep_kernel<<<240, 256, 0, stream>>>(qkv_w, proj_w, rpb, rpi, (char*)d_ws);
    win_attn<true><<<NWIN, 384, 0, stream>>>(x, rpi, qkv_w, qkv_b, proj_w,
                                             proj_b, rpb, (const char*)d_ws, out);
  } else {
    win_attn<false><<<NWIN, 384, 0, stream>>>(x, rpi, qkv_w, qkv_b, proj_w,
                                              proj_b, rpb, (const char*)d_ws, out);
  }
}